// Round 11
// baseline (302.744 us; speedup 1.0000x reference)
//
#include <hip/hip_runtime.h>
#include <hip/hip_bf16.h>
#include <math.h>

// Problem constants
#define B_    32
#define N_    1024
#define DIM_  512
#define HEAD_ 8
#define HD_   64        // head dim
#define WSP   32        // sqrt(N)
#define M2    256       // kv spatial positions (16*16)
#define CDIM  1024      // 2*DIM
#define KCONV 4608      // DIM*3*3
#define EPS_  1e-5f
#define SCALE_ 0.044194173824159216f  // DIM^-0.5
#define PW    34        // padded spatial side (32 + 2 halo)

typedef __attribute__((ext_vector_type(8))) short bf16x8;
typedef __attribute__((ext_vector_type(4))) float f32x4_t;
typedef const __attribute__((address_space(1))) void gas_t;   // global addr space
typedef __attribute__((address_space(3))) void las_t;         // LDS addr space

__device__ __forceinline__ ushort f2b(float x) {
  __hip_bfloat16 h = __float2bfloat16(x);
  return *reinterpret_cast<const ushort*>(&h);
}

// ---------------------------------------------------------------------------
// fp32 -> bf16 cast, 4 elems/thread (weights)
// ---------------------------------------------------------------------------
__global__ __launch_bounds__(256) void cast_f32_bf16_kernel(
    const float* __restrict__ in, ushort* __restrict__ out, int n4) {
  int i = blockIdx.x * 256 + threadIdx.x;
  if (i >= n4) return;
  float4 v = reinterpret_cast<const float4*>(in)[i];
  ushort4 o;
  o.x = f2b(v.x); o.y = f2b(v.y); o.z = f2b(v.z); o.w = f2b(v.w);
  reinterpret_cast<ushort4*>(out)[i] = o;
}

// ---------------------------------------------------------------------------
// Zero only the halo border of featsp [b][34][34][512]
// ---------------------------------------------------------------------------
__global__ __launch_bounds__(256) void zero_border_kernel(ushort* __restrict__ featsp) {
  int t = blockIdx.x * 256 + threadIdx.x;
  int b = t / 8448, r = t - b * 8448;          // 8448 = 132*64
  int cell = r >> 6, ic8 = (r & 63) * 8;
  int iw, ih;
  if (cell < 34)      { iw = 0;  ih = cell; }
  else if (cell < 68) { iw = 33; ih = cell - 34; }
  else { int e = cell - 68; iw = 1 + (e >> 1); ih = (e & 1) * 33; }
  bf16x8 z = {};
  *reinterpret_cast<bf16x8*>(&featsp[(((size_t)b * PW + iw) * PW + ih) * 512 + ic8]) = z;
}

// ---------------------------------------------------------------------------
// feats f32 [b][n=iw*32+ih][ic] -> zero-padded bf16 [b][iw+1][ih+1][ic]
// ---------------------------------------------------------------------------
__global__ __launch_bounds__(256) void cast_featsp_kernel(
    const float* __restrict__ feats, ushort* __restrict__ featsp) {
  int i = blockIdx.x * 256 + threadIdx.x;       // ushort4 index
  int e = i * 4;
  int b = e >> 19, r = e & 524287;
  int n = r >> 9, ic = r & 511;
  int iw = n >> 5, ih = n & 31;
  float4 v = reinterpret_cast<const float4*>(feats)[i];
  ushort4 o;
  o.x = f2b(v.x); o.y = f2b(v.y); o.z = f2b(v.z); o.w = f2b(v.w);
  size_t dst = (((size_t)b * PW + iw + 1) * PW + ih + 1) * 512 + ic;
  *reinterpret_cast<ushort4*>(&featsp[dst]) = o;
}

// ---------------------------------------------------------------------------
// conv_w [oc][ic*9 + tap] fp32 -> bf16 [oc][tap*512 + ic]
// ---------------------------------------------------------------------------
__global__ __launch_bounds__(256) void permute_convw_kernel(
    const float* __restrict__ in, ushort* __restrict__ out) {
  int oc = blockIdx.y;
  int idx = blockIdx.x * 256 + threadIdx.x;  // [0, 4608)
  int tap = idx >> 9, ic = idx & 511;
  out[(size_t)oc * KCONV + idx] = f2b(in[(size_t)oc * KCONV + ic * 9 + tap]);
}

// ---------------------------------------------------------------------------
// Shared MFMA GEMM body: C[M x N] = A[M x K] * B[N x K]^T
// 128x128 tile, BK=32, 4 waves, global_load_lds(16B) staging into a
// TRIPLE-buffered LDS (2-deep prefetch): every tile's loads get two full
// compute phases to land before their vmcnt wait:
//   iter kt: stage(kt+2) ; s_waitcnt vmcnt(8) ; s_barrier
//            MFMA(cur=kt%3) ; s_barrier
// XCD-chunked swizzle, conflict-free LDS via source-permuted chunk swizzle.
// MODE 0: A = plain bf16 buffer            -> C f32
// MODE 1: A = padded-feats center-tap rows -> C bf16   (q-proj)
// MODE 2: A = padded-feats im2col 3x3 s2   -> C f32 + bias (conv)
// ---------------------------------------------------------------------------
template<int MODE>
__device__ __forceinline__ void gemm_body(
    ushort (*As)[128][32], ushort (*Bs)[128][32],
    int l, int nbn, int nwg,
    const ushort* __restrict__ A, const ushort* __restrict__ featsp,
    const ushort* __restrict__ Bw, float* __restrict__ Cf,
    ushort* __restrict__ Cb, const float* __restrict__ bias,
    int M, int N, int K) {
  const int tid = threadIdx.x;
  const int lane = tid & 63, wid = tid >> 6;
  const int wr = wid >> 1, wc = wid & 1;
  const int v = (l & 7) * (nwg >> 3) + (l >> 3);
  const int bm = (v / nbn) * 128, bn = (v % nbn) * 128;
  const int lrow = lane & 15, lk = lane >> 4;
  const int swz = (lrow >> 1) & 3;         // read-side chunk permutation

  f32x4_t acc[4][4] = {};

  auto stage = [&](int buf, int kt) {
    int k0 = kt << 5;
#pragma unroll
    for (int it = 0; it < 2; ++it) {
      int idx = it * 256 + tid;
      int row = idx >> 2;
      int c = (((idx & 3) ^ ((idx >> 3) & 3))) * 8;  // logical bf16 offset
      const ushort* ga;
      if (MODE == 0) {
        ga = &A[(size_t)(bm + row) * K + k0 + c];
      } else if (MODE == 1) {
        int p = bm + row;
        int b = p >> 10, n = p & 1023;
        int iw = n >> 5, ih = n & 31;
        ga = &featsp[(((size_t)b * PW + iw + 1) * PW + ih + 1) * 512 + k0 + c];
      } else {
        int p = bm + row;
        int b = p >> 8, sp = p & 255;
        int w2 = sp >> 4, h2 = sp & 15;
        int kk = k0 + c;
        int tap = kk >> 9, ic = kk & 511;
        int kh = tap / 3, kw = tap - 3 * kh;
        ga = &featsp[(((size_t)b * PW + 2 * w2 + kh) * PW + 2 * h2 + kw) * 512 + ic];
      }
      __builtin_amdgcn_global_load_lds((gas_t*)ga,
          (las_t*)(&As[buf][0][0] + (size_t)idx * 8), 16, 0, 0);
      const ushort* gb = &Bw[(size_t)(bn + row) * K + k0 + c];
      __builtin_amdgcn_global_load_lds((gas_t*)gb,
          (las_t*)(&Bs[buf][0][0] + (size_t)idx * 8), 16, 0, 0);
    }
  };

  const int NT = K >> 5;
  stage(0, 0);                             // 4 loads in flight
  if (NT > 1) stage(1, 1);                 // 8 in flight
  int cur = 0;
  for (int kt = 0; kt < NT; ++kt) {
    if (kt + 2 < NT) {
      stage(cur == 0 ? 2 : cur - 1, kt + 2);   // (kt+2)%3 ; 12 in flight
      asm volatile("s_waitcnt vmcnt(8)" ::: "memory");   // cur's 4 retired
    } else if (kt + 1 < NT) {
      asm volatile("s_waitcnt vmcnt(4)" ::: "memory");
    } else {
      asm volatile("s_waitcnt vmcnt(0)" ::: "memory");
    }
    __builtin_amdgcn_s_barrier();          // all waves: cur globally ready
    __builtin_amdgcn_sched_barrier(0);
    bf16x8 aF[4], bF[4];
#pragma unroll
    for (int m = 0; m < 4; ++m)
      aF[m] = *reinterpret_cast<const bf16x8*>(
          &As[cur][wr * 64 + m * 16 + lrow][(lk ^ swz) * 8]);
#pragma unroll
    for (int n = 0; n < 4; ++n)
      bF[n] = *reinterpret_cast<const bf16x8*>(
          &Bs[cur][wc * 64 + n * 16 + lrow][(lk ^ swz) * 8]);
#pragma unroll
    for (int m = 0; m < 4; ++m)
#pragma unroll
      for (int n = 0; n < 4; ++n)
        acc[m][n] = __builtin_amdgcn_mfma_f32_16x16x32_bf16(
            aF[m], bF[n], acc[m][n], 0, 0, 0);
    __builtin_amdgcn_sched_barrier(0);
    __builtin_amdgcn_s_barrier();          // cur reads done -> reusable
    cur = (cur == 2) ? 0 : cur + 1;
  }

#pragma unroll
  for (int m = 0; m < 4; ++m) {
#pragma unroll
    for (int n = 0; n < 4; ++n) {
      int col = bn + wc * 64 + n * 16 + lrow;
#pragma unroll
      for (int r = 0; r < 4; ++r) {
        int row = bm + wr * 64 + m * 16 + lk * 4 + r;
        float v2 = acc[m][n][r];
        if (MODE == 2) v2 += bias[col];
        if (MODE == 1) Cb[(size_t)row * N + col] = f2b(v2);
        else Cf[(size_t)row * N + col] = v2;
      }
    }
  }
}

// conv (MODE 2)
__global__ __launch_bounds__(256) void conv_kernel(
    const ushort* __restrict__ featsp, const ushort* __restrict__ convwb,
    const float* __restrict__ conv_b, float* __restrict__ kvf) {
  __shared__ ushort As[3][128][32];
  __shared__ ushort Bs[3][128][32];
  int l = blockIdx.y * gridDim.x + blockIdx.x;
  gemm_body<2>(As, Bs, l, gridDim.x, gridDim.x * gridDim.y,
               nullptr, featsp, convwb, kvf, nullptr, conv_b,
               B_ * M2, CDIM, KCONV);
}

// q-proj (MODE 1)
__global__ __launch_bounds__(256) void qproj_kernel(
    const ushort* __restrict__ featsp, const ushort* __restrict__ wqb,
    ushort* __restrict__ qb) {
  __shared__ ushort As[3][128][32];
  __shared__ ushort Bs[3][128][32];
  int l = blockIdx.y * gridDim.x + blockIdx.x;
  gemm_body<1>(As, Bs, l, gridDim.x, gridDim.x * gridDim.y,
               nullptr, featsp, wqb, nullptr, qb, nullptr,
               B_ * N_, DIM_, DIM_);
}

// out-proj (MODE 0)
__global__ __launch_bounds__(256) void gemm0_kernel(
    const ushort* __restrict__ A, const ushort* __restrict__ Bw,
    float* __restrict__ Cf, int M, int N, int K) {
  __shared__ ushort As[3][128][32];
  __shared__ ushort Bs[3][128][32];
  int l = blockIdx.y * gridDim.x + blockIdx.x;
  gemm_body<0>(As, Bs, l, gridDim.x, gridDim.x * gridDim.y,
               A, nullptr, Bw, Cf, nullptr, nullptr, M, N, K);
}

// ---------------------------------------------------------------------------
// LayerNorm over last dim (1024) of conv output kv[8192][1024] (f32).
// K half -> Kb[bh][256][64] row-major; V half -> Vt[bh][64][256] transposed
// (scatter 2B stores; moves the transpose off attention's critical path).
// ---------------------------------------------------------------------------
__global__ __launch_bounds__(256) void ln_kernel(
    const float* __restrict__ kvin, const float* __restrict__ gamma,
    const float* __restrict__ beta, ushort* __restrict__ Kb,
    ushort* __restrict__ Vt) {
  const int p = blockIdx.x, tid = threadIdx.x;
  float4 x = reinterpret_cast<const float4*>(kvin + (size_t)p * CDIM)[tid];
  float s = x.x + x.y + x.z + x.w;
  float ss = x.x * x.x + x.y * x.y + x.z * x.z + x.w * x.w;
#pragma unroll
  for (int off = 32; off > 0; off >>= 1) {
    s += __shfl_down(s, off);
    ss += __shfl_down(ss, off);
  }
  __shared__ float sb[4], ssb[4];
  if ((tid & 63) == 0) { sb[tid >> 6] = s; ssb[tid >> 6] = ss; }
  __syncthreads();
  float tot = sb[0] + sb[1] + sb[2] + sb[3];
  float tot2 = ssb[0] + ssb[1] + ssb[2] + ssb[3];
  float mu = tot * (1.f / CDIM);
  float var = tot2 * (1.f / CDIM) - mu * mu;
  float rstd = rsqrtf(var + EPS_);
  float4 g = reinterpret_cast<const float4*>(gamma)[tid];
  float4 bb = reinterpret_cast<const float4*>(beta)[tid];
  ushort o0 = f2b((x.x - mu) * rstd * g.x + bb.x);
  ushort o1 = f2b((x.y - mu) * rstd * g.y + bb.y);
  ushort o2 = f2b((x.z - mu) * rstd * g.z + bb.z);
  ushort o3 = f2b((x.w - mu) * rstd * g.w + bb.w);
  int b = p >> 8, j = p & 255;
  int c = tid * 4;
  if (c < DIM_) {
    int h = c >> 6, d = c & 63;
    ushort4 o = make_ushort4(o0, o1, o2, o3);
    *reinterpret_cast<ushort4*>(&Kb[(((size_t)(b * 8 + h)) * M2 + j) * HD_ + d]) = o;
  } else {
    int c2 = c - DIM_;
    int h = c2 >> 6, d = c2 & 63;
    size_t base = ((size_t)(b * 8 + h) * HD_ + d) * M2 + j;
    Vt[base]           = o0;
    Vt[base + M2]      = o1;
    Vt[base + 2 * M2]  = o2;
    Vt[base + 3 * M2]  = o3;
  }
}

// ---------------------------------------------------------------------------
// MFMA attention. One block per (qt, bh): 4 waves, each 32 q-rows.
// LDS = 64 KiB: K swizzled [256][64] in [0,32K) and V^T swizzled [64][256]
// in [32K,64K), BOTH staged via global_load_lds(16B) with source
// pre-swizzle. After QK^T the K region is dead and is reused for the
// per-wave P buffer (8 KiB each), PV split in two 16-q halves. 2 blocks/CU.
// ---------------------------------------------------------------------------
__global__ __launch_bounds__(256) void attn_mfma_kernel(
    const ushort* __restrict__ qb, const ushort* __restrict__ Kb,
    const ushort* __restrict__ Vt, ushort* __restrict__ attob) {
  __shared__ __align__(16) char lds[65536];
  char* lp = lds;
  const int tid = threadIdx.x;
  const int lane = tid & 63, wid = tid >> 6;
  const int lr = lane & 15, lk = lane >> 4;

  // bh-chunked XCD swizzle: each XCD owns 32 consecutive bh with all 8 qt
  const int l = blockIdx.y * 8 + blockIdx.x;       // 2048 blocks
  const int v = (l & 7) * 256 + (l >> 3);
  const int bh = v >> 3, qt = v & 7;
  const int b = bh >> 3, h = bh & 7;

  auto ks_byte = [](int j, int d) -> int {            // K[256][64]
    return (j << 7) + (((d << 1)) ^ ((j & 7) << 4));
  };
  auto vt_byte = [](int d, int j) -> int {            // V^T[64][256]
    return 32768 + (d << 9) + (((j << 1)) ^ ((d & 7) << 4));
  };
  // P (in dead K region): per-wave 8 KiB, 16 q-rows x 256 kv, bf16
  auto p_byte = [](int w, int q4, int kv) -> int {
    return (w << 13) + (q4 << 9) + (((kv << 1)) ^ ((q4 & 7) << 4));
  };

  const ushort* Khead  = Kb + (size_t)bh * M2 * HD_;   // [256][64]
  const ushort* Vthead = Vt + (size_t)bh * HD_ * M2;   // [64][256]

  // ---- stage K and V^T via global_load_lds, source pre-swizzled ----
#pragma unroll
  for (int it = 0; it < 8; ++it) {
    int o = (it * 256 + tid) * 16;                 // K region byte offset
    int j = o >> 7, c = (o >> 4) & 7;
    int cl = c ^ (j & 7);                          // logical chunk
    __builtin_amdgcn_global_load_lds((gas_t*)(Khead + j * HD_ + cl * 8),
        (las_t*)(lp + o), 16, 0, 0);
  }
#pragma unroll
  for (int it = 0; it < 8; ++it) {
    int o = (it * 256 + tid) * 16;                 // V^T region byte offset
    int d = o >> 9, c = (o >> 4) & 31;
    int cl = c ^ (d & 7);
    __builtin_amdgcn_global_load_lds((gas_t*)(Vthead + d * M2 + cl * 8),
        (las_t*)(lp + 32768 + o), 16, 0, 0);
  }

  const int qbase = qt * 128 + wid * 32;
  bf16x8 qf[2][2];
#pragma unroll
  for (int mf = 0; mf < 2; ++mf)
#pragma unroll
    for (int ks = 0; ks < 2; ++ks)
      qf[mf][ks] = *reinterpret_cast<const bf16x8*>(
          qb + ((size_t)(b * N_ + qbase + mf * 16 + lr)) * DIM_ + h * HD_ + ks * 32 + lk * 8);

  __syncthreads();   // staging complete (drains vmcnt)

  // ---- QK^T: S[32 q][256 kv] ----
  f32x4_t sacc[2][16] = {};
  __builtin_amdgcn_s_setprio(1);
#pragma unroll
  for (int ks = 0; ks < 2; ++ks) {
#pragma unroll
    for (int nj = 0; nj < 16; ++nj) {
      bf16x8 kf = *reinterpret_cast<const bf16x8*>(
          lp + ks_byte(nj * 16 + lr, ks * 32 + lk * 8));
      sacc[0][nj] = __builtin_amdgcn_mfma_f32_16x16x32_bf16(qf[0][ks], kf, sacc[0][nj], 0, 0, 0);
      sacc[1][nj] = __builtin_amdgcn_mfma_f32_16x16x32_bf16(qf[1][ks], kf, sacc[1][nj], 0, 0, 0);
    }
  }
  __builtin_amdgcn_s_setprio(0);

  __syncthreads();   // ALL waves done reading K -> K region reusable for P

  float linv[2][4];
  f32x4_t oacc[2][4] = {};
#pragma unroll
  for (int mf = 0; mf < 2; ++mf) {
    // softmax for this 16-q half (no max-subtraction; alpha ~ N(0,0.016))
#pragma unroll
    for (int r = 0; r < 4; ++r) {
      float pv[16];
      float sum = 0.f;
#pragma unroll
      for (int nj = 0; nj < 16; ++nj) {
        pv[nj] = __expf(sacc[mf][nj][r] * SCALE_);
        sum += pv[nj];
      }
      sum += __shfl_xor(sum, 1);
      sum += __shfl_xor(sum, 2);
      sum += __shfl_xor(sum, 4);
      sum += __shfl_xor(sum, 8);
      linv[mf][r] = 1.f / sum;
      int q4 = lk * 4 + r;
#pragma unroll
      for (int nj = 0; nj < 16; ++nj)
        *reinterpret_cast<ushort*>(lp + p_byte(wid, q4, nj * 16 + lr)) = f2b(pv[nj]);
    }
    // PV for this half (per-wave private P region; in-wave LDS ordering)
    __builtin_amdgcn_s_setprio(1);
#pragma unroll
    for (int ks2 = 0; ks2 < 8; ++ks2) {
      bf16x8 pf = *reinterpret_cast<const bf16x8*>(
          lp + p_byte(wid, lr, ks2 * 32 + lk * 8));
#pragma unroll
      for (int df = 0; df < 4; ++df) {
        bf16x8 vf = *reinterpret_cast<const bf16x8*>(
            lp + vt_byte(df * 16 + lr, ks2 * 32 + lk * 8));
        oacc[mf][df] = __builtin_amdgcn_mfma_f32_16x16x32_bf16(pf, vf, oacc[mf][df], 0, 0, 0);
      }
    }
    __builtin_amdgcn_s_setprio(0);
  }

#pragma unroll
  for (int mf = 0; mf < 2; ++mf)
#pragma unroll
    for (int df = 0; df < 4; ++df)
#pragma unroll
      for (int r = 0; r < 4; ++r) {
        int qrow = qbase + mf * 16 + lk * 4 + r;
        int dcol = df * 16 + lr;
        float val = oacc[mf][df][r] * linv[mf][r];
        attob[((size_t)(b * N_ + qrow)) * DIM_ + h * HD_ + dcol] = f2b(val);
      }
}

// ---------------------------------------------------------------------------
extern "C" void kernel_launch(void* const* d_in, const int* in_sizes, int n_in,
                              void* d_out, int out_size, void* d_ws, size_t ws_size,
                              hipStream_t stream) {
  const float* feats  = (const float*)d_in[0];
  const float* W_q    = (const float*)d_in[1];
  const float* conv_w = (const float*)d_in[2];
  const float* conv_b = (const float*)d_in[3];
  const float* ln_g   = (const float*)d_in[4];
  const float* ln_b   = (const float*)d_in[5];
  const float* W_out  = (const float*)d_in[6];
  float* out = (float*)d_out;

  const size_t FP_ELEMS = (size_t)B_ * PW * PW * DIM_;   // 18.94M
  char* ws = (char*)d_ws;
  ushort* featsp = (ushort*)ws;  ws += FP_ELEMS * 2;                  // 37.9 MB
  ushort* qb     = (ushort*)ws;  ws += (size_t)B_ * N_ * DIM_ * 2;    // 33.5 MB
  ushort* attob  = (ushort*)ws;  ws += (size_t)B_ * N_ * DIM_ * 2;    // 33.5 MB
  float*  kvf    = (float*)ws;   ws += (size_t)B_ * M2 * CDIM * 4;    // 33.5 MB
  ushort* convwb = (ushort*)ws;  ws += (size_t)CDIM * KCONV * 2;      //  9.4 MB
  ushort* wqb    = (ushort*)ws;  ws += (size_t)DIM_ * DIM_ * 2;       //  0.5 MB
  ushort* woutb  = (ushort*)ws;  ws += (size_t)DIM_ * DIM_ * 2;       //  0.5 MB
  ushort* Kb     = (ushort*)ws;  ws += (size_t)B_ * HEAD_ * M2 * HD_ * 2;  // 8.4 MB
  ushort* Vt     = (ushort*)ws;  ws += (size_t)B_ * HEAD_ * M2 * HD_ * 2;  // 8.4 MB

  // padded bf16 feats: zero only the halo border, then fill interior
  zero_border_kernel<<<1056, 256, 0, stream>>>(featsp);
  cast_featsp_kernel<<<16384, 256, 0, stream>>>(feats, featsp);
  cast_f32_bf16_kernel<<<256, 256, 0, stream>>>(W_q, wqb, (DIM_ * DIM_) / 4);
  cast_f32_bf16_kernel<<<256, 256, 0, stream>>>(W_out, woutb, (DIM_ * DIM_) / 4);
  permute_convw_kernel<<<dim3(18, CDIM), 256, 0, stream>>>(conv_w, convwb);

  // q = feats @ W_q^T  -> bf16
  qproj_kernel<<<dim3(DIM_ / 128, (B_ * N_) / 128), 256, 0, stream>>>(
      featsp, wqb, qb);

  // kv_pre = conv(feats) + bias (implicit im2col from padded feats)
  conv_kernel<<<dim3(CDIM / 128, (B_ * M2) / 128), 256, 0, stream>>>(
      featsp, convwb, conv_b, kvf);

  // LayerNorm -> Kb (row-major) + Vt (transposed)
  ln_kernel<<<B_ * M2, 256, 0, stream>>>(kvf, ln_g, ln_b, Kb, Vt);

  // MFMA attention (K + V^T LDS-staged via global_load_lds) -> attob
  attn_mfma_kernel<<<dim3(8, B_ * HEAD_), 256, 0, stream>>>(qb, Kb, Vt, attob);

  // out = attout @ W_out^T
  gemm0_kernel<<<dim3(DIM_ / 128, (B_ * N_) / 128), 256, 0, stream>>>(
      attob, woutb, out, B_ * N_, DIM_, DIM_);
}

// Round 12
// 270.515 us; speedup vs baseline: 1.1191x; 1.1191x over previous
//
#include <hip/hip_runtime.h>
#include <hip/hip_bf16.h>
#include <math.h>

// Problem constants
#define B_    32
#define N_    1024
#define DIM_  512
#define HEAD_ 8
#define HD_   64        // head dim
#define WSP   32        // sqrt(N)
#define M2    256       // kv spatial positions (16*16)
#define CDIM  1024      // 2*DIM
#define KCONV 4608      // DIM*3*3
#define EPS_  1e-5f
#define SCALE_ 0.044194173824159216f  // DIM^-0.5
#define PW    34        // padded spatial side (32 + 2 halo)

typedef __attribute__((ext_vector_type(8))) short bf16x8;
typedef __attribute__((ext_vector_type(4))) float f32x4_t;
typedef const __attribute__((address_space(1))) void gas_t;   // global addr space
typedef __attribute__((address_space(3))) void las_t;         // LDS addr space

__device__ __forceinline__ ushort f2b(float x) {
  __hip_bfloat16 h = __float2bfloat16(x);
  return *reinterpret_cast<const ushort*>(&h);
}

// ---------------------------------------------------------------------------
// Merged prep: blocks [0,1056) zero featsp halo border;
// [1056,1312) cast W_q -> bf16; [1312,1568) cast W_out -> bf16.
// ---------------------------------------------------------------------------
__global__ __launch_bounds__(256) void misc_prep_kernel(
    ushort* __restrict__ featsp, const float* __restrict__ W_q,
    ushort* __restrict__ wqb, const float* __restrict__ W_out,
    ushort* __restrict__ woutb) {
  int blk = blockIdx.x;
  if (blk < 1056) {
    int t = blk * 256 + threadIdx.x;           // 270336 = 32*8448 exact
    int b = t / 8448, r = t - b * 8448;        // 8448 = 132*64
    int cell = r >> 6, ic8 = (r & 63) * 8;
    int iw, ih;
    if (cell < 34)      { iw = 0;  ih = cell; }
    else if (cell < 68) { iw = 33; ih = cell - 34; }
    else { int e = cell - 68; iw = 1 + (e >> 1); ih = (e & 1) * 33; }
    bf16x8 z = {};
    *reinterpret_cast<bf16x8*>(&featsp[(((size_t)b * PW + iw) * PW + ih) * 512 + ic8]) = z;
  } else if (blk < 1312) {
    int i = (blk - 1056) * 256 + threadIdx.x;  // [0, 65536)
    float4 v = reinterpret_cast<const float4*>(W_q)[i];
    ushort4 o;
    o.x = f2b(v.x); o.y = f2b(v.y); o.z = f2b(v.z); o.w = f2b(v.w);
    reinterpret_cast<ushort4*>(wqb)[i] = o;
  } else {
    int i = (blk - 1312) * 256 + threadIdx.x;
    float4 v = reinterpret_cast<const float4*>(W_out)[i];
    ushort4 o;
    o.x = f2b(v.x); o.y = f2b(v.y); o.z = f2b(v.z); o.w = f2b(v.w);
    reinterpret_cast<ushort4*>(woutb)[i] = o;
  }
}

// ---------------------------------------------------------------------------
// feats f32 [b][n=iw*32+ih][ic] -> zero-padded bf16 [b][iw+1][ih+1][ic]
// ---------------------------------------------------------------------------
__global__ __launch_bounds__(256) void cast_featsp_kernel(
    const float* __restrict__ feats, ushort* __restrict__ featsp) {
  int i = blockIdx.x * 256 + threadIdx.x;       // ushort4 index
  int e = i * 4;
  int b = e >> 19, r = e & 524287;
  int n = r >> 9, ic = r & 511;
  int iw = n >> 5, ih = n & 31;
  float4 v = reinterpret_cast<const float4*>(feats)[i];
  ushort4 o;
  o.x = f2b(v.x); o.y = f2b(v.y); o.z = f2b(v.z); o.w = f2b(v.w);
  size_t dst = (((size_t)b * PW + iw + 1) * PW + ih + 1) * 512 + ic;
  *reinterpret_cast<ushort4*>(&featsp[dst]) = o;
}

// ---------------------------------------------------------------------------
// conv_w [oc][ic*9 + tap] fp32 -> bf16 [oc][tap*512 + ic]
// ---------------------------------------------------------------------------
__global__ __launch_bounds__(256) void permute_convw_kernel(
    const float* __restrict__ in, ushort* __restrict__ out) {
  int oc = blockIdx.y;
  int idx = blockIdx.x * 256 + threadIdx.x;  // [0, 4608)
  int tap = idx >> 9, ic = idx & 511;
  out[(size_t)oc * KCONV + idx] = f2b(in[(size_t)oc * KCONV + ic * 9 + tap]);
}

// ---------------------------------------------------------------------------
// Shared MFMA GEMM body (R10 best config): 128x128 tile, BK=32, 4 waves,
// LDS double-buffer, global_load_lds(16B), counted-vmcnt 2-phase loop,
// XCD-chunked swizzle, conflict-free LDS via source-permuted chunk swizzle.
// MODE 0: A = plain bf16 buffer            -> C f32
// MODE 1: A = padded-feats center-tap rows -> C bf16   (q-proj)
// MODE 2: A = padded-feats im2col 3x3 s2   -> C f32 + bias (conv)
// ---------------------------------------------------------------------------
template<int MODE>
__device__ __forceinline__ void gemm_body(
    ushort (*As)[128][32], ushort (*Bs)[128][32],
    int l, int nbn, int nwg,
    const ushort* __restrict__ A, const ushort* __restrict__ featsp,
    const ushort* __restrict__ Bw, float* __restrict__ Cf,
    ushort* __restrict__ Cb, const float* __restrict__ bias,
    int M, int N, int K) {
  const int tid = threadIdx.x;
  const int lane = tid & 63, wid = tid >> 6;
  const int wr = wid >> 1, wc = wid & 1;
  const int v = (l & 7) * (nwg >> 3) + (l >> 3);
  const int bm = (v / nbn) * 128, bn = (v % nbn) * 128;
  const int lrow = lane & 15, lk = lane >> 4;
  const int swz = (lrow >> 1) & 3;         // read-side chunk permutation

  f32x4_t acc[4][4] = {};

  auto stage = [&](int buf, int kt) {
    int k0 = kt << 5;
#pragma unroll
    for (int it = 0; it < 2; ++it) {
      int idx = it * 256 + tid;
      int row = idx >> 2;
      int c = (((idx & 3) ^ ((idx >> 3) & 3))) * 8;  // logical bf16 offset
      const ushort* ga;
      if (MODE == 0) {
        ga = &A[(size_t)(bm + row) * K + k0 + c];
      } else if (MODE == 1) {
        int p = bm + row;
        int b = p >> 10, n = p & 1023;
        int iw = n >> 5, ih = n & 31;
        ga = &featsp[(((size_t)b * PW + iw + 1) * PW + ih + 1) * 512 + k0 + c];
      } else {
        int p = bm + row;
        int b = p >> 8, sp = p & 255;
        int w2 = sp >> 4, h2 = sp & 15;
        int kk = k0 + c;
        int tap = kk >> 9, ic = kk & 511;
        int kh = tap / 3, kw = tap - 3 * kh;
        ga = &featsp[(((size_t)b * PW + 2 * w2 + kh) * PW + 2 * h2 + kw) * 512 + ic];
      }
      __builtin_amdgcn_global_load_lds((gas_t*)ga,
          (las_t*)(&As[buf][0][0] + (size_t)idx * 8), 16, 0, 0);
      const ushort* gb = &Bw[(size_t)(bn + row) * K + k0 + c];
      __builtin_amdgcn_global_load_lds((gas_t*)gb,
          (las_t*)(&Bs[buf][0][0] + (size_t)idx * 8), 16, 0, 0);
    }
  };

  stage(0, 0);
  const int NT = K >> 5;
  for (int kt = 0; kt < NT; ++kt) {
    int cur = kt & 1;
    if (kt + 1 < NT) {
      stage(cur ^ 1, kt + 1);
      asm volatile("s_waitcnt vmcnt(4)" ::: "memory");
    } else {
      asm volatile("s_waitcnt vmcnt(0)" ::: "memory");
    }
    __builtin_amdgcn_s_barrier();
    __builtin_amdgcn_sched_barrier(0);
    bf16x8 aF[4], bF[4];
#pragma unroll
    for (int m = 0; m < 4; ++m)
      aF[m] = *reinterpret_cast<const bf16x8*>(
          &As[cur][wr * 64 + m * 16 + lrow][(lk ^ swz) * 8]);
#pragma unroll
    for (int n = 0; n < 4; ++n)
      bF[n] = *reinterpret_cast<const bf16x8*>(
          &Bs[cur][wc * 64 + n * 16 + lrow][(lk ^ swz) * 8]);
#pragma unroll
    for (int m = 0; m < 4; ++m)
#pragma unroll
      for (int n = 0; n < 4; ++n)
        acc[m][n] = __builtin_amdgcn_mfma_f32_16x16x32_bf16(
            aF[m], bF[n], acc[m][n], 0, 0, 0);
    __builtin_amdgcn_sched_barrier(0);
    __builtin_amdgcn_s_barrier();
  }

#pragma unroll
  for (int m = 0; m < 4; ++m) {
#pragma unroll
    for (int n = 0; n < 4; ++n) {
      int col = bn + wc * 64 + n * 16 + lrow;
#pragma unroll
      for (int r = 0; r < 4; ++r) {
        int row = bm + wr * 64 + m * 16 + lk * 4 + r;
        float v2 = acc[m][n][r];
        if (MODE == 2) v2 += bias[col];
        if (MODE == 1) Cb[(size_t)row * N + col] = f2b(v2);
        else Cf[(size_t)row * N + col] = v2;
      }
    }
  }
}

// conv (MODE 2)
__global__ __launch_bounds__(256) void conv_kernel(
    const ushort* __restrict__ featsp, const ushort* __restrict__ convwb,
    const float* __restrict__ conv_b, float* __restrict__ kvf) {
  __shared__ ushort As[2][128][32];
  __shared__ ushort Bs[2][128][32];
  int l = blockIdx.y * gridDim.x + blockIdx.x;
  gemm_body<2>(As, Bs, l, gridDim.x, gridDim.x * gridDim.y,
               nullptr, featsp, convwb, kvf, nullptr, conv_b,
               B_ * M2, CDIM, KCONV);
}

// q-proj (MODE 1)
__global__ __launch_bounds__(256) void qproj_kernel(
    const ushort* __restrict__ featsp, const ushort* __restrict__ wqb,
    ushort* __restrict__ qb) {
  __shared__ ushort As[2][128][32];
  __shared__ ushort Bs[2][128][32];
  int l = blockIdx.y * gridDim.x + blockIdx.x;
  gemm_body<1>(As, Bs, l, gridDim.x, gridDim.x * gridDim.y,
               nullptr, featsp, wqb, nullptr, qb, nullptr,
               B_ * N_, DIM_, DIM_);
}

// out-proj (MODE 0)
__global__ __launch_bounds__(256) void gemm0_kernel(
    const ushort* __restrict__ A, const ushort* __restrict__ Bw,
    float* __restrict__ Cf, int M, int N, int K) {
  __shared__ ushort As[2][128][32];
  __shared__ ushort Bs[2][128][32];
  int l = blockIdx.y * gridDim.x + blockIdx.x;
  gemm_body<0>(As, Bs, l, gridDim.x, gridDim.x * gridDim.y,
               A, nullptr, Bw, Cf, nullptr, nullptr, M, N, K);
}

// ---------------------------------------------------------------------------
// LayerNorm over last dim (1024) of conv output kv[8192][1024] (f32).
// K half -> Kb[bh][256][64] row-major; V half -> Vt[bh][64][256] transposed
// (scatter 2B stores; moves the transpose off attention's critical path).
// ---------------------------------------------------------------------------
__global__ __launch_bounds__(256) void ln_kernel(
    const float* __restrict__ kvin, const float* __restrict__ gamma,
    const float* __restrict__ beta, ushort* __restrict__ Kb,
    ushort* __restrict__ Vt) {
  const int p = blockIdx.x, tid = threadIdx.x;
  float4 x = reinterpret_cast<const float4*>(kvin + (size_t)p * CDIM)[tid];
  float s = x.x + x.y + x.z + x.w;
  float ss = x.x * x.x + x.y * x.y + x.z * x.z + x.w * x.w;
#pragma unroll
  for (int off = 32; off > 0; off >>= 1) {
    s += __shfl_down(s, off);
    ss += __shfl_down(ss, off);
  }
  __shared__ float sb[4], ssb[4];
  if ((tid & 63) == 0) { sb[tid >> 6] = s; ssb[tid >> 6] = ss; }
  __syncthreads();
  float tot = sb[0] + sb[1] + sb[2] + sb[3];
  float tot2 = ssb[0] + ssb[1] + ssb[2] + ssb[3];
  float mu = tot * (1.f / CDIM);
  float var = tot2 * (1.f / CDIM) - mu * mu;
  float rstd = rsqrtf(var + EPS_);
  float4 g = reinterpret_cast<const float4*>(gamma)[tid];
  float4 bb = reinterpret_cast<const float4*>(beta)[tid];
  ushort o0 = f2b((x.x - mu) * rstd * g.x + bb.x);
  ushort o1 = f2b((x.y - mu) * rstd * g.y + bb.y);
  ushort o2 = f2b((x.z - mu) * rstd * g.z + bb.z);
  ushort o3 = f2b((x.w - mu) * rstd * g.w + bb.w);
  int b = p >> 8, j = p & 255;
  int c = tid * 4;
  if (c < DIM_) {
    int h = c >> 6, d = c & 63;
    ushort4 o = make_ushort4(o0, o1, o2, o3);
    *reinterpret_cast<ushort4*>(&Kb[(((size_t)(b * 8 + h)) * M2 + j) * HD_ + d]) = o;
  } else {
    int c2 = c - DIM_;
    int h = c2 >> 6, d = c2 & 63;
    size_t base = ((size_t)(b * 8 + h) * HD_ + d) * M2 + j;
    Vt[base]           = o0;
    Vt[base + M2]      = o1;
    Vt[base + 2 * M2]  = o2;
    Vt[base + 3 * M2]  = o3;
  }
}

// ---------------------------------------------------------------------------
// MFMA attention, ONE block per (b,h): 512 threads = 8 waves, K/V staged
// ONCE (vs 8x before). LDS 128 KiB: K swz [256][64] @0, V^T swz [64][256]
// @32K, per-wave private P (8 KiB x 8) @64K. ONE barrier total (post-
// staging); afterwards every wave runs 4 independent q-passes of 32 rows:
// Q-load -> QK^T -> softmax -> P-write(private) -> PV -> store.
// ---------------------------------------------------------------------------
__global__ __launch_bounds__(512, 2) void attn_mfma_kernel(
    const ushort* __restrict__ qb, const ushort* __restrict__ Kb,
    const ushort* __restrict__ Vt, ushort* __restrict__ attob) {
  __shared__ __align__(16) char lds[131072];
  char* lp = lds;
  const int tid = threadIdx.x;
  const int lane = tid & 63, wid = tid >> 6;   // wid 0..7
  const int lr = lane & 15, lk = lane >> 4;
  const int bh = blockIdx.x;
  const int b = bh >> 3, h = bh & 7;

  auto ks_byte = [](int j, int d) -> int {            // K[256][64] @0
    return (j << 7) + (((d << 1)) ^ ((j & 7) << 4));
  };
  auto vt_byte = [](int d, int j) -> int {            // V^T[64][256] @32K
    return 32768 + (d << 9) + (((j << 1)) ^ ((d & 7) << 4));
  };
  auto p_byte = [](int w, int q4, int kv) -> int {    // P per wave @64K
    return 65536 + (w << 13) + (q4 << 9) + (((kv << 1)) ^ ((q4 & 7) << 4));
  };

  const ushort* Khead  = Kb + (size_t)bh * M2 * HD_;   // [256][64]
  const ushort* Vthead = Vt + (size_t)bh * HD_ * M2;   // [64][256]

  // ---- stage K and V^T once via global_load_lds, source pre-swizzled ----
#pragma unroll
  for (int it = 0; it < 4; ++it) {
    int o = (it * 512 + tid) * 16;                 // K region byte offset
    int j = o >> 7, c = (o >> 4) & 7;
    int cl = c ^ (j & 7);
    __builtin_amdgcn_global_load_lds((gas_t*)(Khead + j * HD_ + cl * 8),
        (las_t*)(lp + o), 16, 0, 0);
  }
#pragma unroll
  for (int it = 0; it < 4; ++it) {
    int o = (it * 512 + tid) * 16;                 // V^T region byte offset
    int d = o >> 9, c = (o >> 4) & 31;
    int cl = c ^ (d & 7);
    __builtin_amdgcn_global_load_lds((gas_t*)(Vthead + d * M2 + cl * 8),
        (las_t*)(lp + 32768 + o), 16, 0, 0);
  }

  __syncthreads();   // staging complete; the ONLY block-wide barrier

  for (int qp = 0; qp < 4; ++qp) {
    const int qbase = qp * 256 + wid * 32;
    bf16x8 qf[2][2];
#pragma unroll
    for (int mf = 0; mf < 2; ++mf)
#pragma unroll
      for (int ks = 0; ks < 2; ++ks)
        qf[mf][ks] = *reinterpret_cast<const bf16x8*>(
            qb + ((size_t)(b * N_ + qbase + mf * 16 + lr)) * DIM_ + h * HD_ + ks * 32 + lk * 8);

    // ---- QK^T: S[32 q][256 kv] ----
    f32x4_t sacc[2][16] = {};
    __builtin_amdgcn_s_setprio(1);
#pragma unroll
    for (int ks = 0; ks < 2; ++ks) {
#pragma unroll
      for (int nj = 0; nj < 16; ++nj) {
        bf16x8 kf = *reinterpret_cast<const bf16x8*>(
            lp + ks_byte(nj * 16 + lr, ks * 32 + lk * 8));
        sacc[0][nj] = __builtin_amdgcn_mfma_f32_16x16x32_bf16(qf[0][ks], kf, sacc[0][nj], 0, 0, 0);
        sacc[1][nj] = __builtin_amdgcn_mfma_f32_16x16x32_bf16(qf[1][ks], kf, sacc[1][nj], 0, 0, 0);
      }
    }
    __builtin_amdgcn_s_setprio(0);

    float linv[2][4];
    f32x4_t oacc[2][4] = {};
#pragma unroll
    for (int mf = 0; mf < 2; ++mf) {
      // softmax (no max-subtraction; alpha ~ N(0,0.016))
#pragma unroll
      for (int r = 0; r < 4; ++r) {
        float pv[16];
        float sum = 0.f;
#pragma unroll
        for (int nj = 0; nj < 16; ++nj) {
          pv[nj] = __expf(sacc[mf][nj][r] * SCALE_);
          sum += pv[nj];
        }
        sum += __shfl_xor(sum, 1);
        sum += __shfl_xor(sum, 2);
        sum += __shfl_xor(sum, 4);
        sum += __shfl_xor(sum, 8);
        linv[mf][r] = 1.f / sum;
        int q4 = lk * 4 + r;
#pragma unroll
        for (int nj = 0; nj < 16; ++nj)
          *reinterpret_cast<ushort*>(lp + p_byte(wid, q4, nj * 16 + lr)) = f2b(pv[nj]);
      }
      // PV for this 16-q half (per-wave private P; in-wave ordering)
      __builtin_amdgcn_s_setprio(1);
#pragma unroll
      for (int ks2 = 0; ks2 < 8; ++ks2) {
        bf16x8 pf = *reinterpret_cast<const bf16x8*>(
            lp + p_byte(wid, lr, ks2 * 32 + lk * 8));
#pragma unroll
        for (int df = 0; df < 4; ++df) {
          bf16x8 vf = *reinterpret_cast<const bf16x8*>(
              lp + vt_byte(df * 16 + lr, ks2 * 32 + lk * 8));
          oacc[mf][df] = __builtin_amdgcn_mfma_f32_16x16x32_bf16(pf, vf, oacc[mf][df], 0, 0, 0);
        }
      }
      __builtin_amdgcn_s_setprio(0);
    }

#pragma unroll
    for (int mf = 0; mf < 2; ++mf)
#pragma unroll
      for (int df = 0; df < 4; ++df)
#pragma unroll
        for (int r = 0; r < 4; ++r) {
          int qrow = qbase + mf * 16 + lk * 4 + r;
          int dcol = df * 16 + lr;
          float val = oacc[mf][df][r] * linv[mf][r];
          attob[((size_t)(b * N_ + qrow)) * DIM_ + h * HD_ + dcol] = f2b(val);
        }
  }
}

// ---------------------------------------------------------------------------
extern "C" void kernel_launch(void* const* d_in, const int* in_sizes, int n_in,
                              void* d_out, int out_size, void* d_ws, size_t ws_size,
                              hipStream_t stream) {
  const float* feats  = (const float*)d_in[0];
  const float* W_q    = (const float*)d_in[1];
  const float* conv_w = (const float*)d_in[2];
  const float* conv_b = (const float*)d_in[3];
  const float* ln_g   = (const float*)d_in[4];
  const float* ln_b   = (const float*)d_in[5];
  const float* W_out  = (const float*)d_in[6];
  float* out = (float*)d_out;

  const size_t FP_ELEMS = (size_t)B_ * PW * PW * DIM_;   // 18.94M
  char* ws = (char*)d_ws;
  ushort* featsp = (ushort*)ws;  ws += FP_ELEMS * 2;                  // 37.9 MB
  ushort* qb     = (ushort*)ws;  ws += (size_t)B_ * N_ * DIM_ * 2;    // 33.5 MB
  ushort* attob  = (ushort*)ws;  ws += (size_t)B_ * N_ * DIM_ * 2;    // 33.5 MB
  float*  kvf    = (float*)ws;   ws += (size_t)B_ * M2 * CDIM * 4;    // 33.5 MB
  ushort* convwb = (ushort*)ws;  ws += (size_t)CDIM * KCONV * 2;      //  9.4 MB
  ushort* wqb    = (ushort*)ws;  ws += (size_t)DIM_ * DIM_ * 2;       //  0.5 MB
  ushort* woutb  = (ushort*)ws;  ws += (size_t)DIM_ * DIM_ * 2;       //  0.5 MB
  ushort* Kb     = (ushort*)ws;  ws += (size_t)B_ * HEAD_ * M2 * HD_ * 2;  // 8.4 MB
  ushort* Vt     = (ushort*)ws;  ws += (size_t)B_ * HEAD_ * M2 * HD_ * 2;  // 8.4 MB

  // merged prep: halo zero + W_q/W_out casts
  misc_prep_kernel<<<1568, 256, 0, stream>>>(featsp, W_q, wqb, W_out, woutb);
  cast_featsp_kernel<<<16384, 256, 0, stream>>>(feats, featsp);
  permute_convw_kernel<<<dim3(18, CDIM), 256, 0, stream>>>(conv_w, convwb);

  // q = feats @ W_q^T  -> bf16
  qproj_kernel<<<dim3(DIM_ / 128, (B_ * N_) / 128), 256, 0, stream>>>(
      featsp, wqb, qb);

  // kv_pre = conv(feats) + bias (implicit im2col from padded feats)
  conv_kernel<<<dim3(CDIM / 128, (B_ * M2) / 128), 256, 0, stream>>>(
      featsp, convwb, conv_b, kvf);

  // LayerNorm -> Kb (row-major) + Vt (transposed)
  ln_kernel<<<B_ * M2, 256, 0, stream>>>(kvf, ln_g, ln_b, Kb, Vt);

  // MFMA attention (one block per bh, single-barrier) -> attob
  attn_mfma_kernel<<<B_ * HEAD_, 512, 0, stream>>>(qb, Kb, Vt, attob);

  // out = attout @ W_out^T
  gemm0_kernel<<<dim3(DIM_ / 128, (B_ * N_) / 128), 256, 0, stream>>>(
      attob, woutb, out, B_ * N_, DIM_, DIM_);
}

// Round 13
// 259.853 us; speedup vs baseline: 1.1651x; 1.0410x over previous
//
#include <hip/hip_runtime.h>
#include <hip/hip_bf16.h>
#include <math.h>

// Problem constants
#define B_    32
#define N_    1024
#define DIM_  512
#define HEAD_ 8
#define HD_   64        // head dim
#define WSP   32        // sqrt(N)
#define M2    256       // kv spatial positions (16*16)
#define CDIM  1024      // 2*DIM
#define KCONV 4608      // DIM*3*3
#define KHALF 2304      // conv K-split chunk
#define EPS_  1e-5f
#define SCALE_ 0.044194173824159216f  // DIM^-0.5
#define PW    34        // padded spatial side (32 + 2 halo)

typedef __attribute__((ext_vector_type(8))) short bf16x8;
typedef __attribute__((ext_vector_type(4))) float f32x4_t;
typedef const __attribute__((address_space(1))) void gas_t;   // global addr space
typedef __attribute__((address_space(3))) void las_t;         // LDS addr space

__device__ __forceinline__ ushort f2b(float x) {
  __hip_bfloat16 h = __float2bfloat16(x);
  return *reinterpret_cast<const ushort*>(&h);
}

// ---------------------------------------------------------------------------
// Merged prep: blocks [0,1056) zero featsp halo border;
// [1056,1312) cast W_q -> bf16; [1312,1568) cast W_out -> bf16.
// ---------------------------------------------------------------------------
__global__ __launch_bounds__(256) void misc_prep_kernel(
    ushort* __restrict__ featsp, const float* __restrict__ W_q,
    ushort* __restrict__ wqb, const float* __restrict__ W_out,
    ushort* __restrict__ woutb) {
  int blk = blockIdx.x;
  if (blk < 1056) {
    int t = blk * 256 + threadIdx.x;           // 270336 = 32*8448 exact
    int b = t / 8448, r = t - b * 8448;        // 8448 = 132*64
    int cell = r >> 6, ic8 = (r & 63) * 8;
    int iw, ih;
    if (cell < 34)      { iw = 0;  ih = cell; }
    else if (cell < 68) { iw = 33; ih = cell - 34; }
    else { int e = cell - 68; iw = 1 + (e >> 1); ih = (e & 1) * 33; }
    bf16x8 z = {};
    *reinterpret_cast<bf16x8*>(&featsp[(((size_t)b * PW + iw) * PW + ih) * 512 + ic8]) = z;
  } else if (blk < 1312) {
    int i = (blk - 1056) * 256 + threadIdx.x;  // [0, 65536)
    float4 v = reinterpret_cast<const float4*>(W_q)[i];
    ushort4 o;
    o.x = f2b(v.x); o.y = f2b(v.y); o.z = f2b(v.z); o.w = f2b(v.w);
    reinterpret_cast<ushort4*>(wqb)[i] = o;
  } else {
    int i = (blk - 1312) * 256 + threadIdx.x;
    float4 v = reinterpret_cast<const float4*>(W_out)[i];
    ushort4 o;
    o.x = f2b(v.x); o.y = f2b(v.y); o.z = f2b(v.z); o.w = f2b(v.w);
    reinterpret_cast<ushort4*>(woutb)[i] = o;
  }
}

// ---------------------------------------------------------------------------
// feats f32 [b][n=iw*32+ih][ic] -> zero-padded bf16 [b][iw+1][ih+1][ic]
// ---------------------------------------------------------------------------
__global__ __launch_bounds__(256) void cast_featsp_kernel(
    const float* __restrict__ feats, ushort* __restrict__ featsp) {
  int i = blockIdx.x * 256 + threadIdx.x;       // ushort4 index
  int e = i * 4;
  int b = e >> 19, r = e & 524287;
  int n = r >> 9, ic = r & 511;
  int iw = n >> 5, ih = n & 31;
  float4 v = reinterpret_cast<const float4*>(feats)[i];
  ushort4 o;
  o.x = f2b(v.x); o.y = f2b(v.y); o.z = f2b(v.z); o.w = f2b(v.w);
  size_t dst = (((size_t)b * PW + iw + 1) * PW + ih + 1) * 512 + ic;
  *reinterpret_cast<ushort4*>(&featsp[dst]) = o;
}

// ---------------------------------------------------------------------------
// conv_w [oc][ic*9 + tap] fp32 -> bf16 [oc][tap*512 + ic]
// ---------------------------------------------------------------------------
__global__ __launch_bounds__(256) void permute_convw_kernel(
    const float* __restrict__ in, ushort* __restrict__ out) {
  int oc = blockIdx.y;
  int idx = blockIdx.x * 256 + threadIdx.x;  // [0, 4608)
  int tap = idx >> 9, ic = idx & 511;
  out[(size_t)oc * KCONV + idx] = f2b(in[(size_t)oc * KCONV + ic * 9 + tap]);
}

// ---------------------------------------------------------------------------
// NEW conv: 256x256 tile, BK=64, 512 threads = 8 waves (2M x 4N), per-wave
// 128x64 output (8x4 fragments). K-split z=2 (grid 4x32x2 = 256 blocks =
// 1/CU, 2 waves/SIMD). LDS 128 KiB: per buffer A[256][64] + B[256][64],
// 16B-chunk XOR swizzle (ch ^= row&7) applied on global SOURCE (linear
// global_load_lds dest) and on read. Counted-vmcnt cross-tile prefetch:
// MFMA:ds_read ratio 2.67 (vs 2.0 at 128^2) -> MFMA-dominant.
// z==0 writes kvf (+bias), z==1 writes kvp1; LN sums.
// ---------------------------------------------------------------------------
__global__ __launch_bounds__(512, 2) void conv256_kernel(
    const ushort* __restrict__ featsp, const ushort* __restrict__ convwb,
    const float* __restrict__ conv_b, float* __restrict__ kvf,
    float* __restrict__ kvp1) {
  __shared__ __align__(16) ushort lds[2][32768];   // 2 x 64 KB
  const int tid = threadIdx.x;                 // 0..511
  const int lane = tid & 63, wid = tid >> 6;   // 8 waves
  const int wr = wid >> 2, wc = wid & 3;       // 2M x 4N
  const int lrow = lane & 15, lk = lane >> 4;
  const int kz = blockIdx.z;
  const int koff = kz * KHALF;

  // XCD swizzle within z-slice (nwg=128, %8==0 -> bijective)
  const int l = blockIdx.y * gridDim.x + blockIdx.x;   // 0..127
  const int v = (l & 7) * 16 + (l >> 3);
  const int bm = (v >> 2) * 256;               // nbn = 4
  const int bn = (v & 3) * 256;
  const int bimg = bm >> 8;                    // one image per bm-tile

  f32x4_t acc[8][4] = {};

  auto stage = [&](int buf, int kt) {
    int k0 = koff + (kt << 6);
    // A: 2048 16B-slots (256 rows x 8 chunks); 512 threads x 4
#pragma unroll
    for (int i = 0; i < 4; ++i) {
      int s = i * 512 + tid;
      int row = s >> 3, ch = s & 7;
      int cl = ch ^ (row & 7);                 // logical chunk (involution)
      int kk = k0 + cl * 8;
      int tap = kk >> 9, ic = kk & 511;
      int kh = tap / 3, kw = tap - 3 * kh;
      int w2 = row >> 4, h2 = row & 15;
      const ushort* ga = &featsp[(((size_t)bimg * PW + 2 * w2 + kh) * PW + 2 * h2 + kw) * 512 + ic];
      __builtin_amdgcn_global_load_lds((gas_t*)ga,
          (las_t*)(&lds[buf][0] + (size_t)s * 8), 16, 0, 0);
    }
    // B: same structure
#pragma unroll
    for (int i = 0; i < 4; ++i) {
      int s = i * 512 + tid;
      int row = s >> 3, ch = s & 7;
      int cl = ch ^ (row & 7);
      const ushort* gb = &convwb[(size_t)(bn + row) * KCONV + k0 + cl * 8];
      __builtin_amdgcn_global_load_lds((gas_t*)gb,
          (las_t*)(&lds[buf][16384] + (size_t)s * 8), 16, 0, 0);
    }
  };

  const int NT = KHALF >> 6;                   // 36
  stage(0, 0);
  for (int kt = 0; kt < NT; ++kt) {
    int cur = kt & 1;
    if (kt + 1 < NT) {
      stage(cur ^ 1, kt + 1);                  // 16 in flight
      asm volatile("s_waitcnt vmcnt(8)" ::: "memory");   // cur's 8 retired
    } else {
      asm volatile("s_waitcnt vmcnt(0)" ::: "memory");
    }
    __builtin_amdgcn_s_barrier();
    __builtin_amdgcn_sched_barrier(0);
#pragma unroll
    for (int kk = 0; kk < 2; ++kk) {
      bf16x8 aF[8], bF[4];
#pragma unroll
      for (int m = 0; m < 8; ++m) {
        int row = wr * 128 + m * 16 + lrow;
        int ch = (kk * 4 + lk) ^ (row & 7);
        aF[m] = *reinterpret_cast<const bf16x8*>(&lds[cur][row * 64 + ch * 8]);
      }
#pragma unroll
      for (int n = 0; n < 4; ++n) {
        int row = wc * 64 + n * 16 + lrow;
        int ch = (kk * 4 + lk) ^ (row & 7);
        bF[n] = *reinterpret_cast<const bf16x8*>(&lds[cur][16384 + row * 64 + ch * 8]);
      }
#pragma unroll
      for (int m = 0; m < 8; ++m)
#pragma unroll
        for (int n = 0; n < 4; ++n)
          acc[m][n] = __builtin_amdgcn_mfma_f32_16x16x32_bf16(
              aF[m], bF[n], acc[m][n], 0, 0, 0);
    }
    __builtin_amdgcn_sched_barrier(0);
    __builtin_amdgcn_s_barrier();
  }

  float* Co = kz ? kvp1 : kvf;
#pragma unroll
  for (int m = 0; m < 8; ++m) {
#pragma unroll
    for (int n = 0; n < 4; ++n) {
      int col = bn + wc * 64 + n * 16 + lrow;
#pragma unroll
      for (int r = 0; r < 4; ++r) {
        int row = bm + wr * 128 + m * 16 + lk * 4 + r;
        float v2 = acc[m][n][r];
        if (kz == 0) v2 += conv_b[col];
        Co[(size_t)row * CDIM + col] = v2;
      }
    }
  }
}

// ---------------------------------------------------------------------------
// Shared MFMA GEMM body (R10/R12 config) for q-proj and out-proj.
// ---------------------------------------------------------------------------
template<int MODE>
__device__ __forceinline__ void gemm_body(
    ushort (*As)[128][32], ushort (*Bs)[128][32],
    int l, int nbn, int nwg,
    const ushort* __restrict__ A, const ushort* __restrict__ featsp,
    const ushort* __restrict__ Bw, float* __restrict__ Cf,
    ushort* __restrict__ Cb, int M, int N, int K) {
  const int tid = threadIdx.x;
  const int lane = tid & 63, wid = tid >> 6;
  const int wr = wid >> 1, wc = wid & 1;
  const int v = (l & 7) * (nwg >> 3) + (l >> 3);
  const int bm = (v / nbn) * 128, bn = (v % nbn) * 128;
  const int lrow = lane & 15, lk = lane >> 4;
  const int swz = (lrow >> 1) & 3;

  f32x4_t acc[4][4] = {};

  auto stage = [&](int buf, int kt) {
    int k0 = kt << 5;
#pragma unroll
    for (int it = 0; it < 2; ++it) {
      int idx = it * 256 + tid;
      int row = idx >> 2;
      int c = (((idx & 3) ^ ((idx >> 3) & 3))) * 8;
      const ushort* ga;
      if (MODE == 0) {
        ga = &A[(size_t)(bm + row) * K + k0 + c];
      } else {
        int p = bm + row;
        int b = p >> 10, n = p & 1023;
        int iw = n >> 5, ih = n & 31;
        ga = &featsp[(((size_t)b * PW + iw + 1) * PW + ih + 1) * 512 + k0 + c];
      }
      __builtin_amdgcn_global_load_lds((gas_t*)ga,
          (las_t*)(&As[buf][0][0] + (size_t)idx * 8), 16, 0, 0);
      const ushort* gb = &Bw[(size_t)(bn + row) * K + k0 + c];
      __builtin_amdgcn_global_load_lds((gas_t*)gb,
          (las_t*)(&Bs[buf][0][0] + (size_t)idx * 8), 16, 0, 0);
    }
  };

  stage(0, 0);
  const int NT = K >> 5;
  for (int kt = 0; kt < NT; ++kt) {
    int cur = kt & 1;
    if (kt + 1 < NT) {
      stage(cur ^ 1, kt + 1);
      asm volatile("s_waitcnt vmcnt(4)" ::: "memory");
    } else {
      asm volatile("s_waitcnt vmcnt(0)" ::: "memory");
    }
    __builtin_amdgcn_s_barrier();
    __builtin_amdgcn_sched_barrier(0);
    bf16x8 aF[4], bF[4];
#pragma unroll
    for (int m = 0; m < 4; ++m)
      aF[m] = *reinterpret_cast<const bf16x8*>(
          &As[cur][wr * 64 + m * 16 + lrow][(lk ^ swz) * 8]);
#pragma unroll
    for (int n = 0; n < 4; ++n)
      bF[n] = *reinterpret_cast<const bf16x8*>(
          &Bs[cur][wc * 64 + n * 16 + lrow][(lk ^ swz) * 8]);
#pragma unroll
    for (int m = 0; m < 4; ++m)
#pragma unroll
      for (int n = 0; n < 4; ++n)
        acc[m][n] = __builtin_amdgcn_mfma_f32_16x16x32_bf16(
            aF[m], bF[n], acc[m][n], 0, 0, 0);
    __builtin_amdgcn_sched_barrier(0);
    __builtin_amdgcn_s_barrier();
  }

#pragma unroll
  for (int m = 0; m < 4; ++m) {
#pragma unroll
    for (int n = 0; n < 4; ++n) {
      int col = bn + wc * 64 + n * 16 + lrow;
#pragma unroll
      for (int r = 0; r < 4; ++r) {
        int row = bm + wr * 64 + m * 16 + lk * 4 + r;
        float v2 = acc[m][n][r];
        if (MODE == 1) Cb[(size_t)row * N + col] = f2b(v2);
        else Cf[(size_t)row * N + col] = v2;
      }
    }
  }
}

// q-proj (MODE 1)
__global__ __launch_bounds__(256) void qproj_kernel(
    const ushort* __restrict__ featsp, const ushort* __restrict__ wqb,
    ushort* __restrict__ qb) {
  __shared__ ushort As[2][128][32];
  __shared__ ushort Bs[2][128][32];
  int l = blockIdx.y * gridDim.x + blockIdx.x;
  gemm_body<1>(As, Bs, l, gridDim.x, gridDim.x * gridDim.y,
               nullptr, featsp, wqb, nullptr, qb, B_ * N_, DIM_, DIM_);
}

// out-proj (MODE 0)
__global__ __launch_bounds__(256) void gemm0_kernel(
    const ushort* __restrict__ A, const ushort* __restrict__ Bw,
    float* __restrict__ Cf, int M, int N, int K) {
  __shared__ ushort As[2][128][32];
  __shared__ ushort Bs[2][128][32];
  int l = blockIdx.y * gridDim.x + blockIdx.x;
  gemm_body<0>(As, Bs, l, gridDim.x, gridDim.x * gridDim.y,
               A, nullptr, Bw, Cf, nullptr, M, N, K);
}

// ---------------------------------------------------------------------------
// LayerNorm over last dim (1024) of conv partials p0+p1 (f32).
// K half -> Kb[bh][256][64] row-major; V half -> Vt[bh][64][256] transposed.
// ---------------------------------------------------------------------------
__global__ __launch_bounds__(256) void ln_kernel(
    const float* __restrict__ kvp0, const float* __restrict__ kvp1,
    const float* __restrict__ gamma, const float* __restrict__ beta,
    ushort* __restrict__ Kb, ushort* __restrict__ Vt) {
  const int p = blockIdx.x, tid = threadIdx.x;
  float4 a = reinterpret_cast<const float4*>(kvp0 + (size_t)p * CDIM)[tid];
  float4 b4 = reinterpret_cast<const float4*>(kvp1 + (size_t)p * CDIM)[tid];
  float4 x = make_float4(a.x + b4.x, a.y + b4.y, a.z + b4.z, a.w + b4.w);
  float s = x.x + x.y + x.z + x.w;
  float ss = x.x * x.x + x.y * x.y + x.z * x.z + x.w * x.w;
#pragma unroll
  for (int off = 32; off > 0; off >>= 1) {
    s += __shfl_down(s, off);
    ss += __shfl_down(ss, off);
  }
  __shared__ float sb[4], ssb[4];
  if ((tid & 63) == 0) { sb[tid >> 6] = s; ssb[tid >> 6] = ss; }
  __syncthreads();
  float tot = sb[0] + sb[1] + sb[2] + sb[3];
  float tot2 = ssb[0] + ssb[1] + ssb[2] + ssb[3];
  float mu = tot * (1.f / CDIM);
  float var = tot2 * (1.f / CDIM) - mu * mu;
  float rstd = rsqrtf(var + EPS_);
  float4 g = reinterpret_cast<const float4*>(gamma)[tid];
  float4 bb = reinterpret_cast<const float4*>(beta)[tid];
  ushort o0 = f2b((x.x - mu) * rstd * g.x + bb.x);
  ushort o1 = f2b((x.y - mu) * rstd * g.y + bb.y);
  ushort o2 = f2b((x.z - mu) * rstd * g.z + bb.z);
  ushort o3 = f2b((x.w - mu) * rstd * g.w + bb.w);
  int b = p >> 8, j = p & 255;
  int c = tid * 4;
  if (c < DIM_) {
    int h = c >> 6, d = c & 63;
    ushort4 o = make_ushort4(o0, o1, o2, o3);
    *reinterpret_cast<ushort4*>(&Kb[(((size_t)(b * 8 + h)) * M2 + j) * HD_ + d]) = o;
  } else {
    int c2 = c - DIM_;
    int h = c2 >> 6, d = c2 & 63;
    size_t base = ((size_t)(b * 8 + h) * HD_ + d) * M2 + j;
    Vt[base]           = o0;
    Vt[base + M2]      = o1;
    Vt[base + 2 * M2]  = o2;
    Vt[base + 3 * M2]  = o3;
  }
}

// ---------------------------------------------------------------------------
// MFMA attention (R12): ONE block per (b,h), 512 threads = 8 waves, K/V
// staged once, single barrier, per-wave private P. LDS 128 KiB.
// ---------------------------------------------------------------------------
__global__ __launch_bounds__(512, 2) void attn_mfma_kernel(
    const ushort* __restrict__ qb, const ushort* __restrict__ Kb,
    const ushort* __restrict__ Vt, ushort* __restrict__ attob) {
  __shared__ __align__(16) char lds[131072];
  char* lp = lds;
  const int tid = threadIdx.x;
  const int lane = tid & 63, wid = tid >> 6;   // wid 0..7
  const int lr = lane & 15, lk = lane >> 4;
  const int bh = blockIdx.x;
  const int b = bh >> 3, h = bh & 7;

  auto ks_byte = [](int j, int d) -> int {            // K[256][64] @0
    return (j << 7) + (((d << 1)) ^ ((j & 7) << 4));
  };
  auto vt_byte = [](int d, int j) -> int {            // V^T[64][256] @32K
    return 32768 + (d << 9) + (((j << 1)) ^ ((d & 7) << 4));
  };
  auto p_byte = [](int w, int q4, int kv) -> int {    // P per wave @64K
    return 65536 + (w << 13) + (q4 << 9) + (((kv << 1)) ^ ((q4 & 7) << 4));
  };

  const ushort* Khead  = Kb + (size_t)bh * M2 * HD_;   // [256][64]
  const ushort* Vthead = Vt + (size_t)bh * HD_ * M2;   // [64][256]

#pragma unroll
  for (int it = 0; it < 4; ++it) {
    int o = (it * 512 + tid) * 16;
    int j = o >> 7, c = (o >> 4) & 7;
    int cl = c ^ (j & 7);
    __builtin_amdgcn_global_load_lds((gas_t*)(Khead + j * HD_ + cl * 8),
        (las_t*)(lp + o), 16, 0, 0);
  }
#pragma unroll
  for (int it = 0; it < 4; ++it) {
    int o = (it * 512 + tid) * 16;
    int d = o >> 9, c = (o >> 4) & 31;
    int cl = c ^ (d & 7);
    __builtin_amdgcn_global_load_lds((gas_t*)(Vthead + d * M2 + cl * 8),
        (las_t*)(lp + 32768 + o), 16, 0, 0);
  }

  __syncthreads();   // the ONLY block-wide barrier

  for (int qp = 0; qp < 4; ++qp) {
    const int qbase = qp * 256 + wid * 32;
    bf16x8 qf[2][2];
#pragma unroll
    for (int mf = 0; mf < 2; ++mf)
#pragma unroll
      for (int ks = 0; ks < 2; ++ks)
        qf[mf][ks] = *reinterpret_cast<const bf16x8*>(
            qb + ((size_t)(b * N_ + qbase + mf * 16 + lr)) * DIM_ + h * HD_ + ks * 32 + lk * 8);

    f32x4_t sacc[2][16] = {};
    __builtin_amdgcn_s_setprio(1);
#pragma unroll
    for (int ks = 0; ks < 2; ++ks) {
#pragma unroll
      for (int nj = 0; nj < 16; ++nj) {
        bf16x8 kf = *reinterpret_cast<const bf16x8*>(
            lp + ks_byte(nj * 16 + lr, ks * 32 + lk * 8));
        sacc[0][nj] = __builtin_amdgcn_mfma_f32_16x16x32_bf16(qf[0][ks], kf, sacc[0][nj], 0, 0, 0);
        sacc[1][nj] = __builtin_amdgcn_mfma_f32_16x16x32_bf16(qf[1][ks], kf, sacc[1][nj], 0, 0, 0);
      }
    }
    __builtin_amdgcn_s_setprio(0);

    float linv[2][4];
    f32x4_t oacc[2][4] = {};
#pragma unroll
    for (int mf = 0; mf < 2; ++mf) {
#pragma unroll
      for (int r = 0; r < 4; ++r) {
        float pv[16];
        float sum = 0.f;
#pragma unroll
        for (int nj = 0; nj < 16; ++nj) {
          pv[nj] = __expf(sacc[mf][nj][r] * SCALE_);
          sum += pv[nj];
        }
        sum += __shfl_xor(sum, 1);
        sum += __shfl_xor(sum, 2);
        sum += __shfl_xor(sum, 4);
        sum += __shfl_xor(sum, 8);
        linv[mf][r] = 1.f / sum;
        int q4 = lk * 4 + r;
#pragma unroll
        for (int nj = 0; nj < 16; ++nj)
          *reinterpret_cast<ushort*>(lp + p_byte(wid, q4, nj * 16 + lr)) = f2b(pv[nj]);
      }
      __builtin_amdgcn_s_setprio(1);
#pragma unroll
      for (int ks2 = 0; ks2 < 8; ++ks2) {
        bf16x8 pf = *reinterpret_cast<const bf16x8*>(
            lp + p_byte(wid, lr, ks2 * 32 + lk * 8));
#pragma unroll
        for (int df = 0; df < 4; ++df) {
          bf16x8 vf = *reinterpret_cast<const bf16x8*>(
              lp + vt_byte(df * 16 + lr, ks2 * 32 + lk * 8));
          oacc[mf][df] = __builtin_amdgcn_mfma_f32_16x16x32_bf16(pf, vf, oacc[mf][df], 0, 0, 0);
        }
      }
      __builtin_amdgcn_s_setprio(0);
    }

#pragma unroll
    for (int mf = 0; mf < 2; ++mf)
#pragma unroll
      for (int df = 0; df < 4; ++df)
#pragma unroll
        for (int r = 0; r < 4; ++r) {
          int qrow = qbase + mf * 16 + lk * 4 + r;
          int dcol = df * 16 + lr;
          float val = oacc[mf][df][r] * linv[mf][r];
          attob[((size_t)(b * N_ + qrow)) * DIM_ + h * HD_ + dcol] = f2b(val);
        }
  }
}

// ---------------------------------------------------------------------------
extern "C" void kernel_launch(void* const* d_in, const int* in_sizes, int n_in,
                              void* d_out, int out_size, void* d_ws, size_t ws_size,
                              hipStream_t stream) {
  const float* feats  = (const float*)d_in[0];
  const float* W_q    = (const float*)d_in[1];
  const float* conv_w = (const float*)d_in[2];
  const float* conv_b = (const float*)d_in[3];
  const float* ln_g   = (const float*)d_in[4];
  const float* ln_b   = (const float*)d_in[5];
  const float* W_out  = (const float*)d_in[6];
  float* out = (float*)d_out;

  const size_t FP_ELEMS = (size_t)B_ * PW * PW * DIM_;   // 18.94M
  char* ws = (char*)d_ws;
  ushort* featsp = (ushort*)ws;  ws += FP_ELEMS * 2;                  // 37.9 MB
  ushort* qb     = (ushort*)ws;  ws += (size_t)B_ * N_ * DIM_ * 2;    // 33.5 MB
  ushort* attob  = (ushort*)ws;  ws += (size_t)B_ * N_ * DIM_ * 2;    // 33.5 MB
  float*  kvf    = (float*)ws;   ws += (size_t)B_ * M2 * CDIM * 4;    // 33.5 MB
  ushort* convwb = (ushort*)ws;  ws += (size_t)CDIM * KCONV * 2;      //  9.4 MB
  ushort* wqb    = (ushort*)ws;  ws += (size_t)DIM_ * DIM_ * 2;       //  0.5 MB
  ushort* woutb  = (ushort*)ws;  ws += (size_t)DIM_ * DIM_ * 2;       //  0.5 MB
  ushort* Kb     = (ushort*)ws;  ws += (size_t)B_ * HEAD_ * M2 * HD_ * 2;  // 8.4 MB
  ushort* Vt     = (ushort*)ws;  ws += (size_t)B_ * HEAD_ * M2 * HD_ * 2;  // 8.4 MB
  // conv K-split partial #1 aliased onto attob (f32 33.5 MB; attob is dead
  // until attention, which runs after LN consumes the partial)
  float* kvp1 = (float*)attob;

  // merged prep: halo zero + W_q/W_out casts
  misc_prep_kernel<<<1568, 256, 0, stream>>>(featsp, W_q, wqb, W_out, woutb);
  cast_featsp_kernel<<<16384, 256, 0, stream>>>(feats, featsp);
  permute_convw_kernel<<<dim3(18, CDIM), 256, 0, stream>>>(conv_w, convwb);

  // q = feats @ W_q^T  -> bf16
  qproj_kernel<<<dim3(DIM_ / 128, (B_ * N_) / 128), 256, 0, stream>>>(
      featsp, wqb, qb);

  // kv_pre = conv(feats) + bias: 256^2 tile, K-split z=2
  conv256_kernel<<<dim3(CDIM / 256, (B_ * M2) / 256, 2), 512, 0, stream>>>(
      featsp, convwb, conv_b, kvf, kvp1);

  // LayerNorm (sums partials) -> Kb (row-major) + Vt (transposed)
  ln_kernel<<<B_ * M2, 256, 0, stream>>>(kvf, kvp1, ln_g, ln_b, Kb, Vt);

  // MFMA attention (one block per bh, single-barrier) -> attob
  attn_mfma_kernel<<<B_ * HEAD_, 512, 0, stream>>>(qb, Kb, Vt, attob);

  // out = attout @ W_out^T
  gemm0_kernel<<<dim3(DIM_ / 128, (B_ * N_) / 128), 256, 0, stream>>>(
      attob, woutb, out, B_ * N_, DIM_, DIM_);
}